// Round 1
// baseline (341.472 us; speedup 1.0000x reference)
//
#include <hip/hip_runtime.h>
#include <stdint.h>

#define A_N 9
#define H_N 50
#define W_N 76
#define HW_N (H_N * W_N)      // 3800
#define N_PROP (A_N * HW_N)   // 34200
#define B_N 4
#define PRE_NMS 4000
#define POST_NMS 300
#define NMS_TH 0.7f
#define SORT_N 4096
#define MASK_WORDS 64

// ---------------------------------------------------------------------------
// Kernel A: decode boxes + build 64-bit sort keys
// key = (sortable(score) << 32) | ~index  -> descending sort == top_k with
// stable lower-index-first tie-break (matches jax.lax.top_k).
// ---------------------------------------------------------------------------
__global__ void decode_kernel(const float* __restrict__ scores,
                              const float* __restrict__ deltas,
                              const float* __restrict__ im_info,
                              const float* __restrict__ anchors,
                              float4* __restrict__ boxes,
                              unsigned long long* __restrict__ keys) {
#pragma clang fp contract(off)
    int gid = blockIdx.x * blockDim.x + threadIdx.x;
    if (gid >= B_N * N_PROP) return;
    int b = gid / N_PROP;
    int n = gid - b * N_PROP;
    int a = n % A_N;
    int hw = n / A_N;
    int hy = hw / W_N;
    int wx = hw - hy * W_N;

    float sx = (float)wx * 16.0f;
    float sy = (float)hy * 16.0f;
    float ax1 = anchors[a * 4 + 0] + sx;
    float ay1 = anchors[a * 4 + 1] + sy;
    float ax2 = anchors[a * 4 + 2] + sx;
    float ay2 = anchors[a * 4 + 3] + sy;
    float aw = ax2 - ax1 + 1.0f;
    float ah = ay2 - ay1 + 1.0f;
    float cx = ax1 + 0.5f * aw;
    float cy = ay1 + 0.5f * ah;

    const float* db = deltas + ((size_t)b * 36 + (size_t)a * 4) * HW_N + hw;
    float d0 = db[0];
    float d1 = db[HW_N];
    float d2 = db[2 * HW_N];
    float d3 = db[3 * HW_N];

    float pcx = d0 * aw + cx;
    float pcy = d1 * ah + cy;
    float pw  = expf(d2) * aw;
    float ph  = expf(d3) * ah;

    float x1 = pcx - 0.5f * pw;
    float y1 = pcy - 0.5f * ph;
    float x2 = pcx + 0.5f * pw;
    float y2 = pcy + 0.5f * ph;

    float xhi = im_info[b * 3 + 1] - 1.0f;
    float yhi = im_info[b * 3 + 0] - 1.0f;
    x1 = fminf(fmaxf(x1, 0.0f), xhi);
    y1 = fminf(fmaxf(y1, 0.0f), yhi);
    x2 = fminf(fmaxf(x2, 0.0f), xhi);
    y2 = fminf(fmaxf(y2, 0.0f), yhi);

    boxes[gid] = make_float4(x1, y1, x2, y2);

    float s = scores[((size_t)b * A_N + a) * HW_N + hw];
    unsigned f = __float_as_uint(s);
    unsigned sk = f ^ ((f & 0x80000000u) ? 0xFFFFFFFFu : 0x80000000u);
    keys[gid] = ((unsigned long long)sk << 32) | (unsigned)(~(unsigned)n);
}

// ---------------------------------------------------------------------------
// Kernel B: per-image exact top-4000 (radix select) + bitonic sort descending
// One block per image. LDS: 16KB hist + 32KB keys.
// ---------------------------------------------------------------------------
__global__ __launch_bounds__(1024) void select_sort_kernel(
    const unsigned long long* __restrict__ keys,
    const float4* __restrict__ boxes,
    float4* __restrict__ sortedBoxes) {
    __shared__ unsigned hist[4096];
    __shared__ unsigned long long skeys[SORT_N];
    __shared__ unsigned coarse[64];
    __shared__ int sh_bucket;
    __shared__ int sh_rank;
    __shared__ unsigned sh_cnt;

    int b = blockIdx.x;
    int tid = threadIdx.x;
    const unsigned long long* K = keys + (size_t)b * N_PROP;

    unsigned long long prefix = 0ull, pmask = 0ull;
    int rank = PRE_NMS;  // we want the 4000th-largest key
    const int shifts[6] = {52, 40, 28, 16, 4, 0};
    const unsigned bmasks[6] = {0xFFFu, 0xFFFu, 0xFFFu, 0xFFFu, 0xFFFu, 0xFu};

    for (int pass = 0; pass < 6; ++pass) {
        int shift = shifts[pass];
        unsigned bm = bmasks[pass];
        for (int i = tid; i < 4096; i += 1024) hist[i] = 0u;
        __syncthreads();
        for (int n = tid; n < N_PROP; n += 1024) {
            unsigned long long k = K[n];
            if ((k & pmask) == prefix)
                atomicAdd(&hist[(unsigned)((k >> shift) & bm)], 1u);
        }
        __syncthreads();
        if (tid < 64) {
            unsigned s = 0;
            for (int j = 0; j < 64; ++j) s += hist[tid * 64 + j];
            coarse[tid] = s;
        }
        __syncthreads();
        if (tid == 0) {
            int r = rank;
            int cb = 63;
            while (cb > 0 && (int)coarse[cb] < r) { r -= (int)coarse[cb]; --cb; }
            int j = 63;
            while (j > 0 && (int)hist[cb * 64 + j] < r) { r -= (int)hist[cb * 64 + j]; --j; }
            sh_bucket = cb * 64 + j;
            sh_rank = r;
        }
        __syncthreads();
        prefix |= ((unsigned long long)(unsigned)sh_bucket) << shift;
        pmask  |= ((unsigned long long)bm) << shift;
        rank = sh_rank;
        __syncthreads();
    }
    // prefix now equals the exact 4000th-largest key (keys are unique).

    if (tid == 0) sh_cnt = 0u;
    __syncthreads();
    for (int n = tid; n < N_PROP; n += 1024) {
        unsigned long long k = K[n];
        if (k >= prefix) {
            unsigned p = atomicAdd(&sh_cnt, 1u);
            if (p < SORT_N) skeys[p] = k;
        }
    }
    __syncthreads();
    int cnt = (int)sh_cnt;  // == 4000 (keys unique)
    for (int p = cnt + tid; p < SORT_N; p += 1024) skeys[p] = 0ull;

    // bitonic sort, descending
    for (unsigned kk = 2; kk <= SORT_N; kk <<= 1) {
        for (unsigned j = kk >> 1; j > 0; j >>= 1) {
            __syncthreads();
            for (unsigned i = tid; i < SORT_N; i += 1024) {
                unsigned ixj = i ^ j;
                if (ixj > i) {
                    unsigned long long x = skeys[i], y = skeys[ixj];
                    bool desc = ((i & kk) == 0);
                    bool sw = desc ? (x < y) : (x > y);
                    if (sw) { skeys[i] = y; skeys[ixj] = x; }
                }
            }
        }
    }
    __syncthreads();

    for (int r = tid; r < SORT_N; r += 1024) {
        float4 bx = make_float4(0.f, 0.f, 0.f, 0.f);
        if (r < cnt && r < PRE_NMS) {
            unsigned idx = ~(unsigned)(skeys[r] & 0xFFFFFFFFull);
            if (idx < N_PROP) bx = boxes[(size_t)b * N_PROP + idx];
        }
        sortedBoxes[(size_t)b * SORT_N + r] = bx;
    }
}

// ---------------------------------------------------------------------------
// Kernel C: suppression bitmask, 64x64 tiles, upper triangle (cc >= rc).
// Lower-triangle words are left unwritten (poison) -- provably never read
// at a time it matters: bits there cover j < i, checked only before row i ORs.
// ---------------------------------------------------------------------------
__global__ void iou_mask_kernel(const float4* __restrict__ sortedBoxes,
                                unsigned long long* __restrict__ mask) {
#pragma clang fp contract(off)
    int rc = blockIdx.x, cc = blockIdx.y, b = blockIdx.z;
    if (cc < rc) return;
    int t = threadIdx.x;
    __shared__ float4 colb[64];
    colb[t] = sortedBoxes[(size_t)b * SORT_N + cc * 64 + t];
    __syncthreads();
    int r = rc * 64 + t;
    float4 rb = sortedBoxes[(size_t)b * SORT_N + r];
    float rarea = (rb.z - rb.x) * (rb.w - rb.y);
    unsigned long long word = 0ull;
    for (int c = 0; c < 64; ++c) {
        int j = cc * 64 + c;
        float4 cb = colb[c];
        float carea = (cb.z - cb.x) * (cb.w - cb.y);
        float ltx = fmaxf(rb.x, cb.x);
        float lty = fmaxf(rb.y, cb.y);
        float rbx = fminf(rb.z, cb.z);
        float rby = fminf(rb.w, cb.w);
        float iw = fmaxf(rbx - ltx, 0.0f);
        float ih = fmaxf(rby - lty, 0.0f);
        float inter = iw * ih;
        float iou = inter / (rarea + carea - inter + 1e-9f);
        if (iou > NMS_TH && j > r) word |= (1ull << c);
    }
    mask[((size_t)b * SORT_N + r) * MASK_WORDS + cc] = word;
}

// ---------------------------------------------------------------------------
// Kernel D: serial greedy scan (one wave per image) + output write.
// Early-exits once 300 boxes are kept (rank >= 300 is dropped by reference).
// ---------------------------------------------------------------------------
__device__ inline unsigned long long bcast64(unsigned long long v, int src) {
    int lo = (int)(v & 0xFFFFFFFFull);
    int hi = (int)(v >> 32);
    lo = __shfl(lo, src);
    hi = __shfl(hi, src);
    return ((unsigned long long)(unsigned)hi << 32) | (unsigned)lo;
}

__global__ void nms_scan_kernel(const unsigned long long* __restrict__ mask,
                                const float4* __restrict__ sortedBoxes,
                                float* __restrict__ out) {
    int b = blockIdx.x;
    int lane = threadIdx.x;  // 0..63
    const unsigned long long* M = mask + (size_t)b * SORT_N * MASK_WORDS;
    __shared__ int kept_idx[POST_NMS];

    unsigned long long removed = 0ull;
    unsigned long long cur = 0ull;
    int kcnt = 0;
    unsigned long long m_next = M[lane];   // row 0, this lane's word
    unsigned long long mw_next = M[0];     // row 0, diagonal word

    for (int i = 0; i < PRE_NMS; ++i) {
        unsigned long long mrow = m_next;
        unsigned long long mw = mw_next;
        int inext = i + 1;  // row 4000 exists (SORT_N=4096), fully built
        m_next = M[(size_t)inext * MASK_WORDS + lane];
        mw_next = M[(size_t)inext * MASK_WORDS + (inext >> 6)];
        int w = i >> 6;
        int bit = i & 63;
        if (bit == 0) cur = bcast64(removed, w);
        bool kept = ((cur >> bit) & 1ull) == 0ull;
        if (kept) {
            removed |= mrow;
            cur |= mw;
            if (lane == 0) kept_idx[kcnt] = i;
            ++kcnt;
            if (kcnt >= POST_NMS) break;
        }
    }
    __syncthreads();
    for (int r = lane; r < POST_NMS; r += 64) {
        float* o = out + ((size_t)b * POST_NMS + r) * 5;
        float4 bx = make_float4(0.f, 0.f, 0.f, 0.f);
        if (r < kcnt) bx = sortedBoxes[(size_t)b * SORT_N + kept_idx[r]];
        o[0] = (float)b;
        o[1] = bx.x;
        o[2] = bx.y;
        o[3] = bx.z;
        o[4] = bx.w;
    }
}

// ---------------------------------------------------------------------------
extern "C" void kernel_launch(void* const* d_in, const int* in_sizes, int n_in,
                              void* d_out, int out_size, void* d_ws, size_t ws_size,
                              hipStream_t stream) {
    const float* scores  = (const float*)d_in[0];
    const float* deltas  = (const float*)d_in[1];
    const float* im_info = (const float*)d_in[2];
    const float* anchors = (const float*)d_in[3];
    float* out = (float*)d_out;

    char* ws = (char*)d_ws;
    size_t off = 0;
    float4* boxes = (float4*)(ws + off);
    off += (size_t)B_N * N_PROP * sizeof(float4);
    off = (off + 255) & ~(size_t)255;
    unsigned long long* keys = (unsigned long long*)(ws + off);
    off += (size_t)B_N * N_PROP * sizeof(unsigned long long);
    off = (off + 255) & ~(size_t)255;
    float4* sortedBoxes = (float4*)(ws + off);
    off += (size_t)B_N * SORT_N * sizeof(float4);
    off = (off + 255) & ~(size_t)255;
    unsigned long long* mask = (unsigned long long*)(ws + off);
    off += (size_t)B_N * SORT_N * MASK_WORDS * sizeof(unsigned long long);
    // total ~11.6 MB of ws

    int total = B_N * N_PROP;
    decode_kernel<<<(total + 255) / 256, 256, 0, stream>>>(
        scores, deltas, im_info, anchors, boxes, keys);
    select_sort_kernel<<<B_N, 1024, 0, stream>>>(keys, boxes, sortedBoxes);
    iou_mask_kernel<<<dim3(64, 64, B_N), 64, 0, stream>>>(sortedBoxes, mask);
    nms_scan_kernel<<<B_N, 64, 0, stream>>>(mask, sortedBoxes, out);
}